// Round 5
// baseline (118.860 us; speedup 1.0000x reference)
//
#include <hip/hip_runtime.h>

#define NN 5000
#define NF 4
#define NT 12
#define NC 600
#define NE 160000
#define FT 48   // NF*NT
#define LOG2E 1.4426950408889634f

typedef float v2f __attribute__((ext_vector_type(2)));

// ws layout (float offsets):
//   dis   [0,      5000)
//   cnt   [5000,  10000)   int: per-target edge count
//   base  [10000, 15001)   int: CSR offsets
//   rank  [16000, 176000)  int: edge rank within its target bucket
//   eid   [176000,336000)  int: bucketed edge id (CSR adjacency)
//   agg   [336000,576000)
//   Mz    [576000,578400)  betaz [578400,579000)
//   Mh    [579000,581400)  betah [581400,582000)
//   probs [582000,582012)

__global__ void k_init(int* __restrict__ cnt) {
    int i = blockIdx.x * blockDim.x + threadIdx.x;
    if (i < NN) cnt[i] = 0;
}

// rank within bucket via atomic; coalesced rank write
__global__ void k_count(const int* __restrict__ ei, int* __restrict__ cnt,
                        int* __restrict__ rank) {
    int e = blockIdx.x * blockDim.x + threadIdx.x;
    if (e < NE) rank[e] = atomicAdd(&cnt[ei[NE + e]], 1);
}

// single-block exclusive scan of cnt[0..NN) -> base
#define SCAN_CHUNK 20
__global__ __launch_bounds__(256) void k_scan(const int* __restrict__ cnt,
                                              int* __restrict__ base) {
    __shared__ int part[256];
    int t = threadIdx.x;
    int start = t * SCAN_CHUNK;
    int s = 0;
#pragma unroll
    for (int k = 0; k < SCAN_CHUNK; ++k) {
        int idx = start + k;
        if (idx < NN) s += cnt[idx];
    }
    part[t] = s;
    __syncthreads();
    for (int off = 1; off < 256; off <<= 1) {
        int v = (t >= off) ? part[t - off] : 0;
        __syncthreads();
        part[t] += v;
        __syncthreads();
    }
    int running = (t == 0) ? 0 : part[t - 1];
#pragma unroll
    for (int k = 0; k < SCAN_CHUNK; ++k) {
        int idx = start + k;
        if (idx < NN) {
            base[idx] = running;
            running += cnt[idx];
        }
    }
    if (t == 255) base[NN] = part[255];
}

// deterministic-position scatter: ONE 4B store per edge, no atomics
__global__ void k_scatter(const int* __restrict__ ei, const int* __restrict__ base,
                          const int* __restrict__ rank, int* __restrict__ eid) {
    int e = blockIdx.x * blockDim.x + threadIdx.x;
    if (e < NE) eid[base[ei[NE + e]] + rank[e]] = e;
}

// per-node degree from bucketed edges, then dis = rsqrt(deg)
__global__ __launch_bounds__(64) void k_deg_dis(const float* __restrict__ w,
                                                const int* __restrict__ base,
                                                const int* __restrict__ eid,
                                                float* __restrict__ dis) {
    int n = blockIdx.x;
    int lane = threadIdx.x;
    int b0 = base[n], b1 = base[n + 1];
    float s = 0.f;
    for (int j = b0 + lane; j < b1; j += 64) s += w[eid[j]];
#pragma unroll
    for (int off = 32; off > 0; off >>= 1) s += __shfl_down(s, off, 64);
    if (lane == 0) dis[n] = rsqrtf(1.0f + s);
}

// one 64-thread block per node: gather incident edges, accumulate agg in regs
__global__ __launch_bounds__(64) void k_gather(
        const float* __restrict__ x, const float* __restrict__ dis,
        const float* __restrict__ w, const int* __restrict__ ei,
        const int* __restrict__ base, const int* __restrict__ eid,
        float* __restrict__ agg) {
    int n = blockIdx.x;
    int lane = threadIdx.x;
    int b0 = base[n], b1 = base[n + 1];
    float dn = dis[n];
    float acc = 0.f;
    if (lane < FT) acc = dn * x[n * FT + lane];
    int j = b0;
    for (; j + 3 < b1; j += 4) {
        int e0 = eid[j], e1 = eid[j + 1], e2 = eid[j + 2], e3 = eid[j + 3];
        int s0 = ei[e0], s1 = ei[e1], s2 = ei[e2], s3 = ei[e3];
        float n0 = dis[s0] * w[e0];
        float n1 = dis[s1] * w[e1];
        float n2 = dis[s2] * w[e2];
        float n3 = dis[s3] * w[e3];
        if (lane < FT) {
            acc += n0 * x[s0 * FT + lane];
            acc += n1 * x[s1 * FT + lane];
            acc += n2 * x[s2 * FT + lane];
            acc += n3 * x[s3 * FT + lane];
        }
    }
    for (; j < b1; ++j) {
        int e0 = eid[j];
        int s0 = ei[e0];
        float n0 = dis[s0] * w[e0];
        if (lane < FT) acc += n0 * x[s0 * FT + lane];
    }
    if (lane < FT) agg[n * FT + lane] = dn * acc;
}

// One wave per output element (see R3). Pre-scales M for exp2 domain.
__global__ __launch_bounds__(256) void k_weights(
        const float* __restrict__ Wz, const float* __restrict__ bz,
        const float* __restrict__ Wh, const float* __restrict__ bh,
        const float* __restrict__ Wlz, const float* __restrict__ blz,
        const float* __restrict__ Wlh, const float* __restrict__ blh,
        const float* __restrict__ att,
        float* __restrict__ Mz, float* __restrict__ betaz,
        float* __restrict__ Mh, float* __restrict__ betah,
        float* __restrict__ probs) {
    int wid = blockIdx.x * 4 + (threadIdx.x >> 6);
    int lane = threadIdx.x & 63;
    if (wid >= 6012) return;

    if (wid < 6000) {
        const float* va;
        const float* vb;
        float scale, bias = 0.f;
        if (wid < 2400) {
            int f = wid / NC, d = wid % NC;
            va = Wz + f * NC; vb = Wlz + d * (2 * NC); scale = LOG2E;
        } else if (wid < 4800) {
            int j = wid - 2400;
            int f = j / NC, d = j % NC;
            va = Wh + f * NC; vb = Wlh + d * (2 * NC); scale = 2.0f * LOG2E;
        } else if (wid < 5400) {
            int d = wid - 4800;
            va = bz; vb = Wlz + d * (2 * NC); scale = LOG2E; bias = blz[d];
        } else {
            int d = wid - 5400;
            va = bh; vb = Wlh + d * (2 * NC); scale = 2.0f * LOG2E; bias = blh[d];
        }
        float s = 0.f;
        for (int c = lane; c < NC; c += 64) s = fmaf(va[c], vb[c], s);
#pragma unroll
        for (int off = 32; off > 0; off >>= 1) s += __shfl_down(s, off, 64);
        if (lane == 0) {
            float r = scale * (bias + s);
            if (wid < 2400) Mz[wid] = r;
            else if (wid < 4800) Mh[wid - 2400] = r;
            else if (wid < 5400) betaz[wid - 4800] = r;
            else betah[wid - 5400] = r;
        }
    } else if (lane == 0) {
        int t = wid - 6000;
        float m = att[0];
        for (int k = 1; k < NT; ++k) m = fmaxf(m, att[k]);
        float ssum = 0.f;
        for (int k = 0; k < NT; ++k) ssum += __expf(att[k] - m);
        probs[t] = __expf(att[t] - m) / ssum;
    }
}

// out[n*12+t] = bhead[t]  (bias pre-init; k_gate accumulates on top)
__global__ void k_outinit(const float* __restrict__ bhead, float* __restrict__ out) {
    int i = blockIdx.x * blockDim.x + threadIdx.x;
    if (i < NN * NT) out[i] = bhead[i % NT];
}

// thread-per-(n,d) gate eval, packed fp32 over t-pairs, fused head partials.
// grid: (3 d-tiles of 256) x (5000 n)
__global__ __launch_bounds__(256) void k_gate(
        const float* __restrict__ agg,
        const float* __restrict__ Mz, const float* __restrict__ betaz,
        const float* __restrict__ Mh, const float* __restrict__ betah,
        const float* __restrict__ probs,
        const float* __restrict__ Whead,
        float* __restrict__ out) {
    int tid = threadIdx.x;
    int d = blockIdx.x * 256 + tid;
    int n = blockIdx.y;
    bool act = d < NC;
    int dd = act ? d : 0;

    // agg row for node n: 48 floats, broadcast across the block (L1-hit)
    const float4* ag4 = (const float4*)(agg + n * FT);
    float A[FT];
#pragma unroll
    for (int i = 0; i < 12; ++i) {
        float4 v = ag4[i];
        A[4 * i] = v.x; A[4 * i + 1] = v.y; A[4 * i + 2] = v.z; A[4 * i + 3] = v.w;
    }
    // A[f*12 + t]

    float mz0 = Mz[0 * NC + dd], mz1 = Mz[1 * NC + dd], mz2 = Mz[2 * NC + dd], mz3 = Mz[3 * NC + dd];
    float mh0 = Mh[0 * NC + dd], mh1 = Mh[1 * NC + dd], mh2 = Mh[2 * NC + dd], mh3 = Mh[3 * NC + dd];
    float Bz = betaz[dd], Bh = betah[dd];

    v2f hacc; hacc.x = 0.f; hacc.y = 0.f;
#pragma unroll
    for (int tp = 0; tp < 6; ++tp) {
        int t0 = 2 * tp;
        v2f a0, a1, a2, a3;
        a0.x = A[0 * NT + t0]; a0.y = A[0 * NT + t0 + 1];
        a1.x = A[1 * NT + t0]; a1.y = A[1 * NT + t0 + 1];
        a2.x = A[2 * NT + t0]; a2.y = A[2 * NT + t0 + 1];
        a3.x = A[3 * NT + t0]; a3.y = A[3 * NT + t0 + 1];
        v2f u; u.x = Bz; u.y = Bz;
        v2f w; w.x = Bh; w.y = Bh;
        u += a0 * mz0; u += a1 * mz1; u += a2 * mz2; u += a3 * mz3;
        w += a0 * mh0; w += a1 * mh1; w += a2 * mh2; w += a3 * mh3;
        v2f eu; eu.x = exp2f(u.x); eu.y = exp2f(u.y);
        v2f ev; ev.x = exp2f(w.x); ev.y = exp2f(w.y);
        v2f den = (eu + 1.f) * (ev + 1.f);
        v2f rd; rd.x = __builtin_amdgcn_rcpf(den.x); rd.y = __builtin_amdgcn_rcpf(den.y);
        v2f pp; pp.x = probs[t0]; pp.y = probs[t0 + 1];
        v2f num = pp * (ev - 1.f);
        hacc += num * rd;
    }
    float r = fmaxf(hacc.x + hacc.y, 0.f);
    if (!act) r = 0.f;

    __shared__ float red[4][NT];
    int wave = tid >> 6, lane = tid & 63;
#pragma unroll
    for (int t = 0; t < NT; ++t) {
        float q = r * Whead[t * NC + dd];
#pragma unroll
        for (int off = 32; off > 0; off >>= 1) q += __shfl_down(q, off, 64);
        if (lane == 0) red[wave][t] = q;
    }
    __syncthreads();
    if (tid < NT) {
        float s = red[0][tid] + red[1][tid] + red[2][tid] + red[3][tid];
        atomicAdd(&out[n * NT + tid], s);
    }
}

extern "C" void kernel_launch(void* const* d_in, const int* in_sizes, int n_in,
                              void* d_out, int out_size, void* d_ws, size_t ws_size,
                              hipStream_t stream) {
    const float* x     = (const float*)d_in[0];
    const int*   ei    = (const int*)d_in[1];
    const float* ea    = (const float*)d_in[2];
    const float* Wz    = (const float*)d_in[3];
    const float* bz    = (const float*)d_in[4];
    const float* Wh    = (const float*)d_in[7];
    const float* bh    = (const float*)d_in[8];
    const float* Wlz   = (const float*)d_in[9];
    const float* blz   = (const float*)d_in[10];
    const float* Wlh   = (const float*)d_in[13];
    const float* blh   = (const float*)d_in[14];
    const float* att   = (const float*)d_in[15];
    const float* Whead = (const float*)d_in[16];
    const float* bhead = (const float*)d_in[17];
    float* out = (float*)d_out;

    float* ws    = (float*)d_ws;
    float* dis   = ws;
    int*   cnt   = (int*)(ws + 5000);
    int*   base  = (int*)(ws + 10000);
    int*   rank  = (int*)(ws + 16000);
    int*   eid   = (int*)(ws + 176000);
    float* agg   = ws + 336000;
    float* Mz    = ws + 576000;
    float* betaz = ws + 578400;
    float* Mh    = ws + 579000;
    float* betah = ws + 581400;
    float* probs = ws + 582000;

    k_init<<<(NN + 255) / 256, 256, 0, stream>>>(cnt);
    k_count<<<(NE + 255) / 256, 256, 0, stream>>>(ei, cnt, rank);
    k_scan<<<1, 256, 0, stream>>>(cnt, base);
    k_scatter<<<(NE + 255) / 256, 256, 0, stream>>>(ei, base, rank, eid);
    k_weights<<<(6012 + 3) / 4, 256, 0, stream>>>(Wz, bz, Wh, bh, Wlz, blz, Wlh, blh,
                                                  att, Mz, betaz, Mh, betah, probs);
    k_outinit<<<(NN * NT + 255) / 256, 256, 0, stream>>>(bhead, out);
    k_deg_dis<<<NN, 64, 0, stream>>>(ea, base, eid, dis);
    k_gather<<<NN, 64, 0, stream>>>(x, dis, ea, ei, base, eid, agg);
    dim3 ggrid(3, NN);
    k_gate<<<ggrid, 256, 0, stream>>>(agg, Mz, betaz, Mh, betah, probs, Whead, out);
}

// Round 6
// 92.463 us; speedup vs baseline: 1.2855x; 1.2855x over previous
//
#include <hip/hip_runtime.h>

#define NN 5000
#define NF 4
#define NT 12
#define NC 600
#define NE 160000
#define FT 48   // NF*NT
#define LOG2E 1.4426950408889634f

typedef float v2f __attribute__((ext_vector_type(2)));

// ws layout (float offsets):
//   dis   [0,      5000)
//   cnt   [5000,  10000)   int: per-target edge count
//   base  [10000, 15001)   int: CSR offsets
//   rank  [16000, 176000)  int: edge rank within its target bucket
//   eid   [176000,336000)  int: bucketed edge id (CSR adjacency)
//   agg   [336000,576000)
//   Mz    [576000,578400)  betaz [578400,579000)
//   Mh    [579000,581400)  betah [581400,582000)
//   probs [582000,582012)

__global__ void k_init(int* __restrict__ cnt) {
    int i = blockIdx.x * blockDim.x + threadIdx.x;
    if (i < NN) cnt[i] = 0;
}

// rank within bucket via atomic; coalesced rank write
__global__ void k_count(const int* __restrict__ ei, int* __restrict__ cnt,
                        int* __restrict__ rank) {
    int e = blockIdx.x * blockDim.x + threadIdx.x;
    if (e < NE) rank[e] = atomicAdd(&cnt[ei[NE + e]], 1);
}

// single-block exclusive scan of cnt[0..NN) -> base
#define SCAN_CHUNK 20
__global__ __launch_bounds__(256) void k_scan(const int* __restrict__ cnt,
                                              int* __restrict__ base) {
    __shared__ int part[256];
    int t = threadIdx.x;
    int start = t * SCAN_CHUNK;
    int s = 0;
#pragma unroll
    for (int k = 0; k < SCAN_CHUNK; ++k) {
        int idx = start + k;
        if (idx < NN) s += cnt[idx];
    }
    part[t] = s;
    __syncthreads();
    for (int off = 1; off < 256; off <<= 1) {
        int v = (t >= off) ? part[t - off] : 0;
        __syncthreads();
        part[t] += v;
        __syncthreads();
    }
    int running = (t == 0) ? 0 : part[t - 1];
#pragma unroll
    for (int k = 0; k < SCAN_CHUNK; ++k) {
        int idx = start + k;
        if (idx < NN) {
            base[idx] = running;
            running += cnt[idx];
        }
    }
    if (t == 255) base[NN] = part[255];
}

// deterministic-position scatter: ONE 4B store per edge, no atomics
__global__ void k_scatter(const int* __restrict__ ei, const int* __restrict__ base,
                          const int* __restrict__ rank, int* __restrict__ eid) {
    int e = blockIdx.x * blockDim.x + threadIdx.x;
    if (e < NE) eid[base[ei[NE + e]] + rank[e]] = e;
}

// per-node degree from bucketed edges, then dis = rsqrt(deg)
__global__ __launch_bounds__(64) void k_deg_dis(const float* __restrict__ w,
                                                const int* __restrict__ base,
                                                const int* __restrict__ eid,
                                                float* __restrict__ dis) {
    int n = blockIdx.x;
    int lane = threadIdx.x;
    int b0 = base[n], b1 = base[n + 1];
    float s = 0.f;
    for (int j = b0 + lane; j < b1; j += 64) s += w[eid[j]];
#pragma unroll
    for (int off = 32; off > 0; off >>= 1) s += __shfl_down(s, off, 64);
    if (lane == 0) dis[n] = rsqrtf(1.0f + s);
}

// one 64-thread block per node: gather incident edges, accumulate agg in regs
__global__ __launch_bounds__(64) void k_gather(
        const float* __restrict__ x, const float* __restrict__ dis,
        const float* __restrict__ w, const int* __restrict__ ei,
        const int* __restrict__ base, const int* __restrict__ eid,
        float* __restrict__ agg) {
    int n = blockIdx.x;
    int lane = threadIdx.x;
    int b0 = base[n], b1 = base[n + 1];
    float dn = dis[n];
    float acc = 0.f;
    if (lane < FT) acc = dn * x[n * FT + lane];
    int j = b0;
    for (; j + 3 < b1; j += 4) {
        int e0 = eid[j], e1 = eid[j + 1], e2 = eid[j + 2], e3 = eid[j + 3];
        int s0 = ei[e0], s1 = ei[e1], s2 = ei[e2], s3 = ei[e3];
        float n0 = dis[s0] * w[e0];
        float n1 = dis[s1] * w[e1];
        float n2 = dis[s2] * w[e2];
        float n3 = dis[s3] * w[e3];
        if (lane < FT) {
            acc += n0 * x[s0 * FT + lane];
            acc += n1 * x[s1 * FT + lane];
            acc += n2 * x[s2 * FT + lane];
            acc += n3 * x[s3 * FT + lane];
        }
    }
    for (; j < b1; ++j) {
        int e0 = eid[j];
        int s0 = ei[e0];
        float n0 = dis[s0] * w[e0];
        if (lane < FT) acc += n0 * x[s0 * FT + lane];
    }
    if (lane < FT) agg[n * FT + lane] = dn * acc;
}

// One wave per output element (see R3). Pre-scales M for exp2 domain.
__global__ __launch_bounds__(256) void k_weights(
        const float* __restrict__ Wz, const float* __restrict__ bz,
        const float* __restrict__ Wh, const float* __restrict__ bh,
        const float* __restrict__ Wlz, const float* __restrict__ blz,
        const float* __restrict__ Wlh, const float* __restrict__ blh,
        const float* __restrict__ att,
        float* __restrict__ Mz, float* __restrict__ betaz,
        float* __restrict__ Mh, float* __restrict__ betah,
        float* __restrict__ probs) {
    int wid = blockIdx.x * 4 + (threadIdx.x >> 6);
    int lane = threadIdx.x & 63;
    if (wid >= 6012) return;

    if (wid < 6000) {
        const float* va;
        const float* vb;
        float scale, bias = 0.f;
        if (wid < 2400) {
            int f = wid / NC, d = wid % NC;
            va = Wz + f * NC; vb = Wlz + d * (2 * NC); scale = LOG2E;
        } else if (wid < 4800) {
            int j = wid - 2400;
            int f = j / NC, d = j % NC;
            va = Wh + f * NC; vb = Wlh + d * (2 * NC); scale = 2.0f * LOG2E;
        } else if (wid < 5400) {
            int d = wid - 4800;
            va = bz; vb = Wlz + d * (2 * NC); scale = LOG2E; bias = blz[d];
        } else {
            int d = wid - 5400;
            va = bh; vb = Wlh + d * (2 * NC); scale = 2.0f * LOG2E; bias = blh[d];
        }
        float s = 0.f;
        for (int c = lane; c < NC; c += 64) s = fmaf(va[c], vb[c], s);
#pragma unroll
        for (int off = 32; off > 0; off >>= 1) s += __shfl_down(s, off, 64);
        if (lane == 0) {
            float r = scale * (bias + s);
            if (wid < 2400) Mz[wid] = r;
            else if (wid < 4800) Mh[wid - 2400] = r;
            else if (wid < 5400) betaz[wid - 4800] = r;
            else betah[wid - 5400] = r;
        }
    } else if (lane == 0) {
        int t = wid - 6000;
        float m = att[0];
        for (int k = 1; k < NT; ++k) m = fmaxf(m, att[k]);
        float ssum = 0.f;
        for (int k = 0; k < NT; ++k) ssum += __expf(att[k] - m);
        probs[t] = __expf(att[t] - m) / ssum;
    }
}

// One single-wave block per node. Lane owns d = it*64+lane, it in [0,10).
// outp[12] lives in registers across all 600 d; one LDS-transpose reduction.
// (1-z)*tanh(h) = (e^v - 1)/((1+e^u)(1+e^v)), u,v pre-scaled for exp2.
__global__ __launch_bounds__(64) void k_main(
        const float* __restrict__ agg,
        const float* __restrict__ Mz, const float* __restrict__ betaz,
        const float* __restrict__ Mh, const float* __restrict__ betah,
        const float* __restrict__ probs,
        const float* __restrict__ Whead, const float* __restrict__ bhead,
        float* __restrict__ out) {
    int n = blockIdx.x;
    int lane = threadIdx.x;

    // agg row for node n: 48 floats, broadcast (L1/L2 hit)
    const float4* ag4 = (const float4*)(agg + n * FT);
    float A[FT];
#pragma unroll
    for (int i = 0; i < 12; ++i) {
        float4 v = ag4[i];
        A[4 * i] = v.x; A[4 * i + 1] = v.y; A[4 * i + 2] = v.z; A[4 * i + 3] = v.w;
    }
    v2f pp[6];
#pragma unroll
    for (int tp = 0; tp < 6; ++tp) { pp[tp].x = probs[2 * tp]; pp[tp].y = probs[2 * tp + 1]; }

    float outp[NT];
#pragma unroll
    for (int t = 0; t < NT; ++t) outp[t] = 0.f;

#pragma unroll
    for (int it = 0; it < 10; ++it) {
        int d = it * 64 + lane;
        bool act = d < NC;
        int dd = act ? d : 0;

        float mz0 = Mz[0 * NC + dd], mz1 = Mz[1 * NC + dd], mz2 = Mz[2 * NC + dd], mz3 = Mz[3 * NC + dd];
        float mh0 = Mh[0 * NC + dd], mh1 = Mh[1 * NC + dd], mh2 = Mh[2 * NC + dd], mh3 = Mh[3 * NC + dd];
        float Bz = betaz[dd], Bh = betah[dd];

        v2f hacc; hacc.x = 0.f; hacc.y = 0.f;
#pragma unroll
        for (int tp = 0; tp < 6; ++tp) {
            int t0 = 2 * tp;
            v2f a0, a1, a2, a3;
            a0.x = A[0 * NT + t0]; a0.y = A[0 * NT + t0 + 1];
            a1.x = A[1 * NT + t0]; a1.y = A[1 * NT + t0 + 1];
            a2.x = A[2 * NT + t0]; a2.y = A[2 * NT + t0 + 1];
            a3.x = A[3 * NT + t0]; a3.y = A[3 * NT + t0 + 1];
            v2f u; u.x = Bz; u.y = Bz;
            v2f w; w.x = Bh; w.y = Bh;
            u += a0 * mz0; u += a1 * mz1; u += a2 * mz2; u += a3 * mz3;
            w += a0 * mh0; w += a1 * mh1; w += a2 * mh2; w += a3 * mh3;
            v2f eu; eu.x = exp2f(u.x); eu.y = exp2f(u.y);
            v2f ev; ev.x = exp2f(w.x); ev.y = exp2f(w.y);
            v2f den = (eu + 1.f) * (ev + 1.f);
            v2f rd; rd.x = __builtin_amdgcn_rcpf(den.x); rd.y = __builtin_amdgcn_rcpf(den.y);
            v2f num = pp[tp] * (ev - 1.f);
            hacc += num * rd;
        }
        float r = act ? fmaxf(hacc.x + hacc.y, 0.f) : 0.f;
#pragma unroll
        for (int t = 0; t < NT; ++t) outp[t] = fmaf(r, Whead[t * NC + dd], outp[t]);
    }

    // LDS transpose reduction: red[t][lane], then lane t sums its row
    __shared__ float red[NT][68];   // 68: float4-aligned, de-conflicted stride
#pragma unroll
    for (int t = 0; t < NT; ++t) red[t][lane] = outp[t];
    __syncthreads();
    if (lane < NT) {
        const float4* row = (const float4*)red[lane];
        float4 s4 = row[0];
#pragma unroll
        for (int j = 1; j < 16; ++j) {
            float4 v = row[j];
            s4.x += v.x; s4.y += v.y; s4.z += v.z; s4.w += v.w;
        }
        out[n * NT + lane] = (s4.x + s4.y) + (s4.z + s4.w) + bhead[lane];
    }
}

extern "C" void kernel_launch(void* const* d_in, const int* in_sizes, int n_in,
                              void* d_out, int out_size, void* d_ws, size_t ws_size,
                              hipStream_t stream) {
    const float* x     = (const float*)d_in[0];
    const int*   ei    = (const int*)d_in[1];
    const float* ea    = (const float*)d_in[2];
    const float* Wz    = (const float*)d_in[3];
    const float* bz    = (const float*)d_in[4];
    const float* Wh    = (const float*)d_in[7];
    const float* bh    = (const float*)d_in[8];
    const float* Wlz   = (const float*)d_in[9];
    const float* blz   = (const float*)d_in[10];
    const float* Wlh   = (const float*)d_in[13];
    const float* blh   = (const float*)d_in[14];
    const float* att   = (const float*)d_in[15];
    const float* Whead = (const float*)d_in[16];
    const float* bhead = (const float*)d_in[17];
    float* out = (float*)d_out;

    float* ws    = (float*)d_ws;
    float* dis   = ws;
    int*   cnt   = (int*)(ws + 5000);
    int*   base  = (int*)(ws + 10000);
    int*   rank  = (int*)(ws + 16000);
    int*   eid   = (int*)(ws + 176000);
    float* agg   = ws + 336000;
    float* Mz    = ws + 576000;
    float* betaz = ws + 578400;
    float* Mh    = ws + 579000;
    float* betah = ws + 581400;
    float* probs = ws + 582000;

    k_init<<<(NN + 255) / 256, 256, 0, stream>>>(cnt);
    k_count<<<(NE + 255) / 256, 256, 0, stream>>>(ei, cnt, rank);
    k_scan<<<1, 256, 0, stream>>>(cnt, base);
    k_scatter<<<(NE + 255) / 256, 256, 0, stream>>>(ei, base, rank, eid);
    k_weights<<<(6012 + 3) / 4, 256, 0, stream>>>(Wz, bz, Wh, bh, Wlz, blz, Wlh, blh,
                                                  att, Mz, betaz, Mh, betah, probs);
    k_deg_dis<<<NN, 64, 0, stream>>>(ea, base, eid, dis);
    k_gather<<<NN, 64, 0, stream>>>(x, dis, ea, ei, base, eid, agg);
    k_main<<<NN, 64, 0, stream>>>(agg, Mz, betaz, Mh, betah, probs, Whead, bhead, out);
}

// Round 7
// 79.494 us; speedup vs baseline: 1.4952x; 1.1632x over previous
//
#include <hip/hip_runtime.h>

#define NN 5000
#define NF 4
#define NT 12
#define NC 600
#define NE 160000
#define FT 48   // NF*NT
#define LOG2E 1.4426950408889634f

typedef float v2f __attribute__((ext_vector_type(2)));

// ws layout (float offsets):
//   dis   [0,      5000)
//   cnt   [5000,  10000)   int
//   base  [10000, 15001)   int
//   rank  [16000, 176000)  int
//   epak  [176000,496000)  int2 (src, w-bits) per bucketed edge
//   agg   [496000,736000)
//   Mz4   [736000,738400)  float4[600]  (f inner, LOG2E-scaled)
//   Mh4   [738400,740800)  float4[600]  (2*LOG2E-scaled)
//   bzh   [740800,742000)  float2[600]  (betaz, betah)
//   WT    [742000,749200)  float[600][12] (Whead transposed)
//   probs [749200,749212)

__global__ void k_init(int* __restrict__ cnt) {
    int i = blockIdx.x * blockDim.x + threadIdx.x;
    if (i < NN) cnt[i] = 0;
}

__global__ void k_count(const int* __restrict__ ei, int* __restrict__ cnt,
                        int* __restrict__ rank) {
    int e = blockIdx.x * blockDim.x + threadIdx.x;
    if (e < NE) rank[e] = atomicAdd(&cnt[ei[NE + e]], 1);
}

#define SCAN_CHUNK 20
__global__ __launch_bounds__(256) void k_scan(const int* __restrict__ cnt,
                                              int* __restrict__ base) {
    __shared__ int part[256];
    int t = threadIdx.x;
    int start = t * SCAN_CHUNK;
    int s = 0;
#pragma unroll
    for (int k = 0; k < SCAN_CHUNK; ++k) {
        int idx = start + k;
        if (idx < NN) s += cnt[idx];
    }
    part[t] = s;
    __syncthreads();
    for (int off = 1; off < 256; off <<= 1) {
        int v = (t >= off) ? part[t - off] : 0;
        __syncthreads();
        part[t] += v;
        __syncthreads();
    }
    int running = (t == 0) ? 0 : part[t - 1];
#pragma unroll
    for (int k = 0; k < SCAN_CHUNK; ++k) {
        int idx = start + k;
        if (idx < NN) {
            base[idx] = running;
            running += cnt[idx];
        }
    }
    if (t == 255) base[NN] = part[255];
}

// deterministic-position scatter of packed (src, weight): one 8B store, no atomics
__global__ void k_scatter(const int* __restrict__ ei, const float* __restrict__ w,
                          const int* __restrict__ base, const int* __restrict__ rank,
                          int2* __restrict__ epak) {
    int e = blockIdx.x * blockDim.x + threadIdx.x;
    if (e < NE) {
        int2 p; p.x = ei[e]; p.y = __float_as_int(w[e]);
        epak[base[ei[NE + e]] + rank[e]] = p;
    }
}

// per-node degree from packed edges (sequential reads), dis = rsqrt(1+deg)
__global__ __launch_bounds__(64) void k_deg_dis(const int2* __restrict__ epak,
                                                const int* __restrict__ base,
                                                float* __restrict__ dis) {
    int n = blockIdx.x;
    int lane = threadIdx.x;
    int b0 = base[n], b1 = base[n + 1];
    float s = 0.f;
    for (int j = b0 + lane; j < b1; j += 64) s += __int_as_float(epak[j].y);
#pragma unroll
    for (int off = 32; off > 0; off >>= 1) s += __shfl_down(s, off, 64);
    if (lane == 0) dis[n] = rsqrtf(1.0f + s);
}

// one 64-thread block per node: gather incident edges, accumulate agg in regs
__global__ __launch_bounds__(64) void k_gather(
        const float* __restrict__ x, const float* __restrict__ dis,
        const int2* __restrict__ epak, const int* __restrict__ base,
        float* __restrict__ agg) {
    int n = blockIdx.x;
    int lane = threadIdx.x;
    int b0 = base[n], b1 = base[n + 1];
    float dn = dis[n];
    float acc = 0.f;
    if (lane < FT) acc = dn * x[n * FT + lane];
    int j = b0;
    for (; j + 3 < b1; j += 4) {
        int2 p0 = epak[j], p1 = epak[j + 1], p2 = epak[j + 2], p3 = epak[j + 3];
        float n0 = dis[p0.x] * __int_as_float(p0.y);
        float n1 = dis[p1.x] * __int_as_float(p1.y);
        float n2 = dis[p2.x] * __int_as_float(p2.y);
        float n3 = dis[p3.x] * __int_as_float(p3.y);
        if (lane < FT) {
            acc += n0 * x[p0.x * FT + lane];
            acc += n1 * x[p1.x * FT + lane];
            acc += n2 * x[p2.x * FT + lane];
            acc += n3 * x[p3.x * FT + lane];
        }
    }
    for (; j < b1; ++j) {
        int2 p0 = epak[j];
        float n0 = dis[p0.x] * __int_as_float(p0.y);
        if (lane < FT) acc += n0 * x[p0.x * FT + lane];
    }
    if (lane < FT) agg[n * FT + lane] = dn * acc;
}

// One wave per output element; writes PACKED layouts for k_main.
__global__ __launch_bounds__(256) void k_weights(
        const float* __restrict__ Wz, const float* __restrict__ bz,
        const float* __restrict__ Wh, const float* __restrict__ bh,
        const float* __restrict__ Wlz, const float* __restrict__ blz,
        const float* __restrict__ Wlh, const float* __restrict__ blh,
        const float* __restrict__ att,
        float* __restrict__ Mz4, float* __restrict__ Mh4,
        float* __restrict__ bzh, float* __restrict__ probs) {
    int wid = blockIdx.x * 4 + (threadIdx.x >> 6);
    int lane = threadIdx.x & 63;
    if (wid >= 6012) return;

    if (wid < 6000) {
        const float* va;
        const float* vb;
        float scale, bias = 0.f;
        if (wid < 2400) {
            int f = wid / NC, d = wid % NC;
            va = Wz + f * NC; vb = Wlz + d * (2 * NC); scale = LOG2E;
        } else if (wid < 4800) {
            int j = wid - 2400;
            int f = j / NC, d = j % NC;
            va = Wh + f * NC; vb = Wlh + d * (2 * NC); scale = 2.0f * LOG2E;
        } else if (wid < 5400) {
            int d = wid - 4800;
            va = bz; vb = Wlz + d * (2 * NC); scale = LOG2E; bias = blz[d];
        } else {
            int d = wid - 5400;
            va = bh; vb = Wlh + d * (2 * NC); scale = 2.0f * LOG2E; bias = blh[d];
        }
        float s = 0.f;
        for (int c = lane; c < NC; c += 64) s = fmaf(va[c], vb[c], s);
#pragma unroll
        for (int off = 32; off > 0; off >>= 1) s += __shfl_down(s, off, 64);
        if (lane == 0) {
            float r = scale * (bias + s);
            if (wid < 2400) {
                int f = wid / NC, d = wid % NC;
                Mz4[d * 4 + f] = r;
            } else if (wid < 4800) {
                int j = wid - 2400;
                int f = j / NC, d = j % NC;
                Mh4[d * 4 + f] = r;
            } else if (wid < 5400) {
                bzh[(wid - 4800) * 2] = r;
            } else {
                bzh[(wid - 5400) * 2 + 1] = r;
            }
        }
    } else if (lane == 0) {
        int t = wid - 6000;
        float m = att[0];
        for (int k = 1; k < NT; ++k) m = fmaxf(m, att[k]);
        float ssum = 0.f;
        for (int k = 0; k < NT; ++k) ssum += __expf(att[k] - m);
        probs[t] = __expf(att[t] - m) / ssum;
    }
}

// transpose Whead[t][d] -> WT[d][t]
__global__ void k_wt(const float* __restrict__ Whead, float* __restrict__ WT) {
    int i = blockIdx.x * blockDim.x + threadIdx.x;
    if (i < NC * NT) WT[i] = Whead[(i % NT) * NC + (i / NT)];
}

// 256-thread block = 4 waves, one NODE per wave. Lane owns d = it*64+lane.
// outp[12] in regs across all 600 d; one wave-private LDS transpose reduce.
__global__ __launch_bounds__(256, 4) void k_main(
        const float* __restrict__ agg,
        const float4* __restrict__ Mz4, const float4* __restrict__ Mh4,
        const float2* __restrict__ bzh, const float* __restrict__ probs,
        const float* __restrict__ WT, const float* __restrict__ bhead,
        float* __restrict__ out) {
    int wid = threadIdx.x >> 6, lane = threadIdx.x & 63;
    int n = blockIdx.x * 4 + wid;

    // agg row as v2f pairs: A2[f*6+tp] = {agg[f][2tp], agg[f][2tp+1]}
    const v2f* ag2 = (const v2f*)(agg + n * FT);
    v2f A2[24];
#pragma unroll
    for (int i = 0; i < 24; ++i) A2[i] = ag2[i];

    v2f pp[6];
#pragma unroll
    for (int tp = 0; tp < 6; ++tp) { pp[tp].x = probs[2 * tp]; pp[tp].y = probs[2 * tp + 1]; }

    float outp[NT];
#pragma unroll
    for (int t = 0; t < NT; ++t) outp[t] = 0.f;

#pragma unroll
    for (int it = 0; it < 10; ++it) {
        int d = it * 64 + lane;
        bool act = d < NC;
        int dd = act ? d : 0;

        float4 mzv = Mz4[dd];
        float4 mhv = Mh4[dd];
        float2 bb = bzh[dd];

        v2f hacc; hacc.x = 0.f; hacc.y = 0.f;
#pragma unroll
        for (int tp = 0; tp < 6; ++tp) {
            v2f u; u.x = bb.x; u.y = bb.x;
            v2f v; v.x = bb.y; v.y = bb.y;
            u += A2[0 * 6 + tp] * mzv.x;
            u += A2[1 * 6 + tp] * mzv.y;
            u += A2[2 * 6 + tp] * mzv.z;
            u += A2[3 * 6 + tp] * mzv.w;
            v += A2[0 * 6 + tp] * mhv.x;
            v += A2[1 * 6 + tp] * mhv.y;
            v += A2[2 * 6 + tp] * mhv.z;
            v += A2[3 * 6 + tp] * mhv.w;
            v2f eu; eu.x = exp2f(u.x); eu.y = exp2f(u.y);
            v2f ev; ev.x = exp2f(v.x); ev.y = exp2f(v.y);
            v2f den = (eu + 1.f) * (ev + 1.f);
            v2f rd; rd.x = __builtin_amdgcn_rcpf(den.x); rd.y = __builtin_amdgcn_rcpf(den.y);
            v2f num = pp[tp] * (ev - 1.f);
            hacc += num * rd;
        }
        float r = act ? fmaxf(hacc.x + hacc.y, 0.f) : 0.f;

        const float4* wt4 = (const float4*)(WT + dd * NT);
        float4 w0 = wt4[0], w1 = wt4[1], w2 = wt4[2];
        outp[0] = fmaf(r, w0.x, outp[0]);  outp[1] = fmaf(r, w0.y, outp[1]);
        outp[2] = fmaf(r, w0.z, outp[2]);  outp[3] = fmaf(r, w0.w, outp[3]);
        outp[4] = fmaf(r, w1.x, outp[4]);  outp[5] = fmaf(r, w1.y, outp[5]);
        outp[6] = fmaf(r, w1.z, outp[6]);  outp[7] = fmaf(r, w1.w, outp[7]);
        outp[8] = fmaf(r, w2.x, outp[8]);  outp[9] = fmaf(r, w2.y, outp[9]);
        outp[10] = fmaf(r, w2.z, outp[10]); outp[11] = fmaf(r, w2.w, outp[11]);
    }

    // wave-private LDS transpose reduction (no barrier needed: same-wave deps)
    __shared__ float red[4][NT][68];
#pragma unroll
    for (int t = 0; t < NT; ++t) red[wid][t][lane] = outp[t];
    if (lane < NT) {
        const float4* row = (const float4*)red[wid][lane];
        float4 s4 = row[0];
#pragma unroll
        for (int j = 1; j < 16; ++j) {
            float4 v = row[j];
            s4.x += v.x; s4.y += v.y; s4.z += v.z; s4.w += v.w;
        }
        out[n * NT + lane] = (s4.x + s4.y) + (s4.z + s4.w) + bhead[lane];
    }
}

extern "C" void kernel_launch(void* const* d_in, const int* in_sizes, int n_in,
                              void* d_out, int out_size, void* d_ws, size_t ws_size,
                              hipStream_t stream) {
    const float* x     = (const float*)d_in[0];
    const int*   ei    = (const int*)d_in[1];
    const float* ea    = (const float*)d_in[2];
    const float* Wz    = (const float*)d_in[3];
    const float* bz    = (const float*)d_in[4];
    const float* Wh    = (const float*)d_in[7];
    const float* bh    = (const float*)d_in[8];
    const float* Wlz   = (const float*)d_in[9];
    const float* blz   = (const float*)d_in[10];
    const float* Wlh   = (const float*)d_in[13];
    const float* blh   = (const float*)d_in[14];
    const float* att   = (const float*)d_in[15];
    const float* Whead = (const float*)d_in[16];
    const float* bhead = (const float*)d_in[17];
    float* out = (float*)d_out;

    float* ws    = (float*)d_ws;
    float* dis   = ws;
    int*   cnt   = (int*)(ws + 5000);
    int*   base  = (int*)(ws + 10000);
    int*   rank  = (int*)(ws + 16000);
    int2*  epak  = (int2*)(ws + 176000);
    float* agg   = ws + 496000;
    float* Mz4   = ws + 736000;
    float* Mh4   = ws + 738400;
    float* bzh   = ws + 740800;
    float* WT    = ws + 742000;
    float* probs = ws + 749200;

    k_init<<<(NN + 255) / 256, 256, 0, stream>>>(cnt);
    k_count<<<(NE + 255) / 256, 256, 0, stream>>>(ei, cnt, rank);
    k_scan<<<1, 256, 0, stream>>>(cnt, base);
    k_scatter<<<(NE + 255) / 256, 256, 0, stream>>>(ei, ea, base, rank, epak);
    k_weights<<<(6012 + 3) / 4, 256, 0, stream>>>(Wz, bz, Wh, bh, Wlz, blz, Wlh, blh,
                                                  att, Mz4, Mh4, bzh, probs);
    k_wt<<<(NC * NT + 255) / 256, 256, 0, stream>>>(Whead, WT);
    k_deg_dis<<<NN, 64, 0, stream>>>(epak, base, dis);
    k_gather<<<NN, 64, 0, stream>>>(x, dis, epak, base, agg);
    k_main<<<NN / 4, 256, 0, stream>>>(agg, (const float4*)Mz4, (const float4*)Mh4,
                                       (const float2*)bzh, probs, WT, bhead, out);
}